// Round 11
// baseline (1960.385 us; speedup 1.0000x reference)
//
#include <hip/hip_runtime.h>
#include <hip/hip_bf16.h>
#include <stdint.h>

#define T_  32
#define B_  32
#define C_  128
#define HS_ 512
#define HW_ 7
#define S_  49
#define CS_  (C_*S_)      // 6272
#define ICS_ (2*C_*S_)    // 12544
#define KH_  1152         // per-half conv K (9*128), kid-major: k = kid*128+ic
#define KL_  6272         // linear K, reordered to k' = s*128+c
#define N_   512

typedef __attribute__((ext_vector_type(8))) short short8;
typedef __attribute__((ext_vector_type(4))) float f32x4;
typedef __hip_bfloat16 bf16;
typedef unsigned long long u64;

union bfbits { bf16 b; short s; };

__device__ __forceinline__ void gl16(const void* g, void* l) {
    __builtin_amdgcn_global_load_lds((const __attribute__((address_space(1))) void*)g,
                                     (__attribute__((address_space(3))) void*)l, 16, 0, 0);
}

__device__ __forceinline__ float sigm_f(float v) { return 1.0f / (1.0f + __expf(-v)); }
__device__ __forceinline__ float tanh_f(float v) { return 1.0f - 2.0f / (__expf(2.0f * v) + 1.0f); }
__device__ __forceinline__ float sel4(float r0, float r1, float r2, float r3, int idx) {
    float a = (idx & 1) ? r1 : r0;
    float b = (idx & 1) ? r3 : r2;
    return (idx & 2) ? b : a;
}

// ---------------------------------------------------------------------------
// Persistent per-batch-group kernel. 256 blocks = 8 n-slices x 32 batches,
// 512 threads. Sync among the 8 blocks of one batch via a monotone per-batch
// atomic counter (single RMW/block/step); h exchanged via RELAXED agent-scope
// atomic loads/stores (coherence-point access, no RMW write-back, no L2
// invalidate -> x/Wx stay L2-hot). Wh slice LDS-resident; h staged to LDS.
// ---------------------------------------------------------------------------
__global__ __launch_bounds__(512, 1) void k_persist(
    const bf16* __restrict__ xT, u64* __restrict__ hx,
    const bf16* __restrict__ WxP, const bf16* __restrict__ WhP,
    const float* __restrict__ bconv, const float* __restrict__ cbuf,
    const float* __restrict__ masks, bf16* __restrict__ chist,
    float* __restrict__ outS, const bf16* __restrict__ zb, int* __restrict__ cnt)
{
    __shared__ __align__(16) bf16 sWh[64 * KH_];   // 147456 B
    __shared__ __align__(16) bf16 sH[50 * 128];    // 12800 B (row 49 = zeros)

    const int tid = threadIdx.x, lane = tid & 63, w = tid >> 6;
    const int wr = w >> 2, wc = w & 3;
    const int nId = blockIdx.x >> 5, b = blockIdx.x & 31;
    const int n0 = nId * 64;

    // ---- Wh slice -> LDS (source-side XOR swizzle, chunk ^= col&7) ---------
#pragma unroll
    for (int i = 0; i < 18; ++i) {
        int ci = i * 512 + tid;            // 9216 = 64 cols x 144 chunks
        int col = ci / 144, s = ci - col * 144;
        gl16(WhP + (size_t)(n0 + col) * KH_ + (size_t)(s ^ (col & 7)) * 8,
             sWh + (size_t)ci * 8);
    }

    // ---- A-row decode (A-frag rows = wr*32+fm*16+(lane&15)) ----------------
    int ayy[2], axx[2]; bool aok[2];
#pragma unroll
    for (int fm = 0; fm < 2; ++fm) {
        int so = wr * 32 + fm * 16 + (lane & 15);
        aok[fm] = so < S_;
        int sc = aok[fm] ? so : 0;
        ayy[fm] = sc / HW_; axx[fm] = sc - ayy[fm] * HW_;
    }
    const int aco = ((lane >> 4) << 3);

    // ---- epilogue rows ------------------------------------------------------
    int er[2]; bool eok[2];
#pragma unroll
    for (int fm = 0; fm < 2; ++fm) {
        er[fm] = wr * 32 + fm * 16 + ((lane >> 4) << 2) + (lane & 3);
        eok[fm] = er[fm] < S_;
    }
    const int chn = (n0 >> 2) + wc * 4 + ((lane & 15) >> 2);

    // ---- c-state ------------------------------------------------------------
    float cst[2];
#pragma unroll
    for (int fm = 0; fm < 2; ++fm)
        cst[fm] = eok[fm] ? cbuf[((size_t)(b * S_ + er[fm]) << 7) + chn] : 0.f;

    // ---- bias ---------------------------------------------------------------
    const int np = n0 + wc * 16 + (lane & 15);
    const float bias = bconv[((np & 3) << 7) + (np >> 2)];

    // ---- h(0) -> LDS (swizzled); zero row 49 -------------------------------
    auto loadH = [&](int buf) {
        const u64* src = hx + (size_t)buf * (32 * 1568) + (size_t)b * 1568;
#pragma unroll
        for (int u = tid; u < 1568; u += 512) {
            u64 v = __hip_atomic_load(src + u, __ATOMIC_RELAXED, __HIP_MEMORY_SCOPE_AGENT);
            int s = u >> 5, cg = u & 31;                  // cg: 8B group (4 ch)
            int phys = (cg >> 1) ^ (s & 15);
            *(u64*)((char*)sH + s * 256 + phys * 16 + (cg & 1) * 8) = v;
        }
    };
    loadH(0);
    if (tid < 32) *(u64*)((char*)sH + 49 * 256 + tid * 8) = 0ULL;
    asm volatile("s_waitcnt vmcnt(0)" ::: "memory");
    __syncthreads();

    // ---- fragment loaders ---------------------------------------------------
    auto ldAH = [&](int kid, int fm, int kh) -> short8 {   // h from LDS
        int ky = kid / 3, kx = kid - 3 * (kid / 3);
        int y2 = ayy[fm] + ky - 1, x2 = axx[fm] + kx - 1;
        bool ok = aok[fm] && (unsigned)y2 < (unsigned)HW_ && (unsigned)x2 < (unsigned)HW_;
        int row = ok ? (y2 * HW_ + x2) : 49;
        int chunk = kh * 4 + (lane >> 4);
        int addr = row * 256 + ((chunk ^ (row & 15)) << 4);
        return *(const short8*)((const char*)sH + addr);
    };
    auto ldB = [&](int kid, int kh) -> short8 {            // Wh from LDS
        int col = wc * 16 + (lane & 15);
        int chunk = kid * 16 + kh * 4 + (lane >> 4);
        int phys = chunk ^ (col & 7);
        return *(const short8*)(sWh + (size_t)col * KH_ + (size_t)phys * 8);
    };
    auto ldAX = [&](const bf16* xsrc, int kid, int fm, int kh) -> short8 {
        int ky = kid / 3, kx = kid - 3 * (kid / 3);
        int y2 = ayy[fm] + ky - 1, x2 = axx[fm] + kx - 1;
        bool ok = aok[fm] && (unsigned)y2 < (unsigned)HW_ && (unsigned)x2 < (unsigned)HW_;
        const bf16* p = ok ? xsrc + (((size_t)(y2 * HW_ + x2)) << 7) + kh * 32 + aco : zb;
        return *(const short8*)p;
    };
    auto ldBx = [&](int kid, int kh) -> short8 {
        int col = n0 + wc * 16 + (lane & 15);
        return *(const short8*)(WxP + (size_t)col * KH_ + kid * 128 + kh * 32 + aco);
    };

    auto gemmH = [&](f32x4 (&acc)[2]) {
#pragma unroll
        for (int kid = 0; kid < 9; ++kid) {
            short8 af[2][4], bq[4];
#pragma unroll
            for (int kh = 0; kh < 4; ++kh) {
                af[0][kh] = ldAH(kid, 0, kh);
                af[1][kh] = ldAH(kid, 1, kh);
                bq[kh] = ldB(kid, kh);
            }
#pragma unroll
            for (int kh = 0; kh < 4; ++kh)
#pragma unroll
                for (int fm = 0; fm < 2; ++fm)
                    acc[fm] = __builtin_amdgcn_mfma_f32_16x16x32_bf16(
                        af[fm][kh], bq[kh], acc[fm], 0, 0, 0);
        }
    };
    auto gemmX = [&](const bf16* xsrc, f32x4 (&acc)[2]) {
#pragma unroll
        for (int kid = 0; kid < 9; ++kid) {
            short8 af[2][4], bq[4];
#pragma unroll
            for (int kh = 0; kh < 4; ++kh) {
                af[0][kh] = ldAX(xsrc, kid, 0, kh);
                af[1][kh] = ldAX(xsrc, kid, 1, kh);
                bq[kh] = ldBx(kid, kh);
            }
#pragma unroll
            for (int kh = 0; kh < 4; ++kh)
#pragma unroll
                for (int fm = 0; fm < 2; ++fm)
                    acc[fm] = __builtin_amdgcn_mfma_f32_16x16x32_bf16(
                        af[fm][kh], bq[kh], acc[fm], 0, 0, 0);
        }
    };

    // ---- recurrence ---------------------------------------------------------
    f32x4 gx[2];
    const int j = lane & 3;
    uint32_t* hxw = (uint32_t*)hx;     // word view for coherent 4B stores

#pragma unroll 1
    for (int t = 0; t < T_; ++t) {
        const bf16* xTt = xT + (((size_t)t * 32 + b) * S_ << 7);
        float mc = masks[t * B_ + b];
        float ma = (t < T_ - 1) ? masks[(t + 1) * B_ + b] : 1.f;
#pragma unroll 1
        for (int rd = 0; rd < 3; ++rd) {
            const int sg = t * 3 + rd;
            const bool last = (sg == 95);
            f32x4 acc[2];
            if (rd == 0) {
                f32x4 b4 = {bias, bias, bias, bias};
                acc[0] = b4; acc[1] = b4;
                gemmX(xTt, acc);
                gx[0] = acc[0]; gx[1] = acc[1];
                gemmH(acc);
            } else {
                acc[0] = gx[0]; acc[1] = gx[1];
                gemmH(acc);
            }

            // ---- epilogue: butterfly gates, c in registers -----------------
#pragma unroll
            for (int fm = 0; fm < 2; ++fm) {
                f32x4 a = acc[fm];
                float s0 = sel4(a[0], a[1], a[2], a[3], j);
                float s1 = __shfl_xor(sel4(a[0], a[1], a[2], a[3], j ^ 1), 1);
                float s2 = __shfl_xor(sel4(a[0], a[1], a[2], a[3], j ^ 2), 2);
                float s3 = __shfl_xor(sel4(a[0], a[1], a[2], a[3], j ^ 3), 3);
                float gi = sel4(s0, s1, s2, s3, j);
                float gf = sel4(s0, s1, s2, s3, j ^ 1);
                float go = sel4(s0, s1, s2, s3, j ^ 2);
                float gg = sel4(s0, s1, s2, s3, j ^ 3);
                float ig = sigm_f(gi), fg = sigm_f(gf), og = sigm_f(go), gv = tanh_f(gg);
                float c = cst[fm];
                if (rd == 0) c *= mc;
                float cn = fg * c + ig * gv;
                cst[fm] = cn;
                float hn = og * tanh_f(cn);

                if (!last) {
                    // paired-channel h store (coherence-point store, no RMW)
                    float hm = hn * ((rd == 2) ? ma : 1.f);
                    bfbits hb; hb.b = __float2bfloat16(hm);
                    unsigned lo = (unsigned)(unsigned short)hb.s;
                    unsigned hi = __shfl_xor(lo, 4);
                    if (((lane >> 2) & 1) == 0 && eok[fm]) {
                        size_t widx = (size_t)((sg + 1) & 1) * (32 * 3136)
                                    + (size_t)b * 3136
                                    + ((er[fm] << 7) + chn >> 1);
                        __hip_atomic_store(hxw + widx, lo | (hi << 16),
                                           __ATOMIC_RELAXED, __HIP_MEMORY_SCOPE_AGENT);
                    }
                }
                if (eok[fm]) {
                    if (rd == 2)
                        chist[((size_t)t * 32 + b) * KL_ + er[fm] * C_ + chn] = __float2bfloat16(cn);
                    if (last) {
                        outS[(size_t)b * ICS_ + chn * S_ + er[fm]] = hn;
                        outS[(size_t)b * ICS_ + (C_ + chn) * S_ + er[fm]] = cn;
                    }
                }
            }

            if (!last) {
                asm volatile("s_waitcnt vmcnt(0)" ::: "memory");   // h stores committed
                __syncthreads();
                if (tid == 0) {
                    __hip_atomic_fetch_add(cnt + b, 1, __ATOMIC_RELAXED, __HIP_MEMORY_SCOPE_AGENT);
                    int target = 8 * (sg + 1);
                    while (__hip_atomic_load(cnt + b, __ATOMIC_RELAXED, __HIP_MEMORY_SCOPE_AGENT) < target)
                        __builtin_amdgcn_s_sleep(1);
                }
                __syncthreads();
                loadH((sg + 1) & 1);
                asm volatile("s_waitcnt vmcnt(0)" ::: "memory");
                __syncthreads();
            }
        }
    }
}

// ---------------------------------------------------------------------------
// Deferred linear: out = relu(chist @ Wlp^T + blin). 64x64 tile, BK=128,
// 3-deep counted-vmcnt pipeline.
// ---------------------------------------------------------------------------
#define PIPE_BARRIER_COUNTED()  do {                                   \
    asm volatile("s_waitcnt vmcnt(8)" ::: "memory");                   \
    __builtin_amdgcn_sched_barrier(0);                                 \
    __builtin_amdgcn_s_barrier();                                      \
    __builtin_amdgcn_sched_barrier(0);                                 \
} while (0)
#define PIPE_BARRIER_DRAIN()  do {                                     \
    asm volatile("s_waitcnt vmcnt(0)" ::: "memory");                   \
    __builtin_amdgcn_sched_barrier(0);                                 \
    __builtin_amdgcn_s_barrier();                                      \
    __builtin_amdgcn_sched_barrier(0);                                 \
} while (0)

__global__ __launch_bounds__(256, 1) void k_lingemm(
    const bf16* __restrict__ Ac, const bf16* __restrict__ Wl,
    const float* __restrict__ blin, float* __restrict__ out)
{
    __shared__ __align__(16) uint8_t smem[98304];
    bf16* sA = (bf16*)smem;
    bf16* sB = (bf16*)(smem + 49152);

    const int tid = threadIdx.x, lane = tid & 63, w = tid >> 6;
    const int wr = w >> 1, wc = w & 1;
    const int m0 = blockIdx.x * 64, n0 = blockIdx.y * 64;
    const int kq = tid & 15, rr = tid >> 4;
    const int swz = ((kq ^ rr) << 3);

    f32x4 acc[2][2];
#pragma unroll
    for (int fn = 0; fn < 2; ++fn) {
        int np = n0 + wc * 32 + fn * 16 + (lane & 15);
        float bv = blin[np];
        f32x4 b4 = {bv, bv, bv, bv};
        acc[0][fn] = b4; acc[1][fn] = b4;
    }

    auto stage = [&](int st, int dbuf) {
        bf16* lA = sA + dbuf * 8192;
        bf16* lB = sB + dbuf * 8192;
#pragma unroll
        for (int q = 0; q < 4; ++q) {
            gl16(Ac + (size_t)(m0 + q * 16 + rr) * KL_ + st * 128 + swz, lA + q * 2048 + w * 512);
            gl16(Wl + (size_t)(n0 + q * 16 + rr) * KL_ + st * 128 + swz, lB + q * 2048 + w * 512);
        }
    };
    auto compute = [&](int dbuf) {
        const bf16* lA = sA + dbuf * 8192;
        const bf16* lB = sB + dbuf * 8192;
        short8 af[2][4], bq[2][4];
#pragma unroll
        for (int kh = 0; kh < 4; ++kh) {
            int c = kh * 4 + (lane >> 4);
            int xr = (c ^ (lane & 15)) << 3;
#pragma unroll
            for (int fm = 0; fm < 2; ++fm) {
                int r = wr * 32 + fm * 16 + (lane & 15);
                af[fm][kh] = *(const short8*)(lA + r * 128 + xr);
            }
#pragma unroll
            for (int fn = 0; fn < 2; ++fn) {
                int r = wc * 32 + fn * 16 + (lane & 15);
                bq[fn][kh] = *(const short8*)(lB + r * 128 + xr);
            }
        }
#pragma unroll
        for (int kh = 0; kh < 4; ++kh)
#pragma unroll
            for (int fm = 0; fm < 2; ++fm)
#pragma unroll
                for (int fn = 0; fn < 2; ++fn)
                    acc[fm][fn] = __builtin_amdgcn_mfma_f32_16x16x32_bf16(
                        af[fm][kh], bq[fn][kh], acc[fm][fn], 0, 0, 0);
    };

    stage(0, 0);
    stage(1, 1);
    PIPE_BARRIER_COUNTED();

    int cur = 0;
#pragma unroll 1
    for (int st = 0; st < 49; ++st) {
        int pre = cur + 2; if (pre >= 3) pre -= 3;
        if (st + 2 < 49) stage(st + 2, pre);
        compute(cur);
        if (st + 2 < 49) { PIPE_BARRIER_COUNTED(); }
        else             { PIPE_BARRIER_DRAIN(); }
        ++cur; if (cur == 3) cur = 0;
    }

#pragma unroll
    for (int fm = 0; fm < 2; ++fm)
#pragma unroll
        for (int fn = 0; fn < 2; ++fn) {
            int col = n0 + wc * 32 + fn * 16 + (lane & 15);
            int rb  = m0 + wr * 32 + fm * 16 + ((lane >> 4) << 2);
#pragma unroll
            for (int jj = 0; jj < 4; ++jj)
                out[(size_t)(rb + jj) * N_ + col] = fmaxf(acc[fm][fn][jj], 0.f);
        }
}

// ---------------------------------------------------------------------------
// Weight prep: split Wconv into Wx/Wh, n' = 4c+gate rows, k = kid*128+ic
// ---------------------------------------------------------------------------
__global__ __launch_bounds__(256) void k_wsplit(const float* __restrict__ Wc,
                                               bf16* __restrict__ WxP, bf16* __restrict__ WhP) {
    int idx = blockIdx.x * 256 + threadIdx.x;     // 512*288
    if (idx >= 512 * 288) return;
    int np = idx / 288, kq = idx % 288;
    int oc = ((np & 3) << 7) + (np >> 2);
    int kk = kq * 8;
    int half = kk >= KH_;
    int krel = kk - half * KH_;
    short8 v;
#pragma unroll
    for (int jj = 0; jj < 8; ++jj) {
        int kr = krel + jj;
        int kid = kr >> 7, ic = (kr & 127) + half * 128;
        bfbits bb; bb.b = __float2bfloat16(Wc[((size_t)oc * 256 + ic) * 9 + kid]);
        v[jj] = bb.s;
    }
    bf16* dst = half ? WhP : WxP;
    *reinterpret_cast<short8*>(dst + (size_t)np * KH_ + krel) = v;
}

// Wlin reorder: k' = s*128+c
__global__ __launch_bounds__(256) void k_wlin2(const float* __restrict__ Wl, bf16* __restrict__ Wp) {
    int idx = blockIdx.x * 256 + threadIdx.x;     // 512*784
    if (idx >= 512 * 784) return;
    int np = idx / 784, kq = idx % 784;
    short8 v;
#pragma unroll
    for (int jj = 0; jj < 8; ++jj) {
        int kp = kq * 8 + jj;
        int s = kp >> 7, c = kp & 127;
        bfbits bb; bb.b = __float2bfloat16(Wl[(size_t)np * KL_ + c * S_ + s]);
        v[jj] = bb.s;
    }
    *reinterpret_cast<short8*>(Wp + (size_t)np * KL_ + kq * 8) = v;
}

// x (T*B, C, 49) f32 -> xT (T*B, 49, 128) bf16
__global__ __launch_bounds__(256) void k_xpose(const float* __restrict__ x, bf16* __restrict__ xT) {
    int idx = blockIdx.x * 256 + threadIdx.x;     // 1024*784
    if (idx >= 1024 * 784) return;
    int r = idx / 784;
    int rem = idx % 784;
    int s = rem / 16, c8 = (rem & 15) * 8;
    const float* sp = x + (size_t)r * CS_ + c8 * S_ + s;
    short8 v;
#pragma unroll
    for (int jj = 0; jj < 8; ++jj) { bfbits bb; bb.b = __float2bfloat16(sp[jj * S_]); v[jj] = bb.s; }
    *reinterpret_cast<short8*>(xT + (((size_t)r * S_ + s) << 7) + c8) = v;
}

// h0*mask0 -> hx[0] bf16 (b,s,c);  c0 -> cbuf f32 (b,s,c)
__global__ __launch_bounds__(256) void k_hcprep(const float* __restrict__ hxs,
                                                const float* __restrict__ mask0,
                                                bf16* __restrict__ hx0, float* __restrict__ cbuf) {
    int idx = blockIdx.x * 256 + threadIdx.x;     // 32*784
    if (idx >= 32 * 784) return;
    int b = idx / 784;
    int rem = idx % 784;
    int s = rem / 16, c8 = (rem & 15) * 8;
    float m = mask0[b];
    const float* hp = hxs + (size_t)b * ICS_ + c8 * S_ + s;
    const float* cp = hp + CS_;
    size_t o = (((size_t)b * S_ + s) << 7) + c8;
    short8 v;
#pragma unroll
    for (int jj = 0; jj < 8; ++jj) {
        bfbits bb; bb.b = __float2bfloat16(hp[jj * S_] * m); v[jj] = bb.s;
        cbuf[o + jj] = cp[jj * S_];
    }
    *reinterpret_cast<short8*>(hx0 + o) = v;
}

__global__ __launch_bounds__(256) void k_zero16(uint4* __restrict__ p, int n) {
    int i = blockIdx.x * 256 + threadIdx.x;
    if (i < n) p[i] = make_uint4(0, 0, 0, 0);
}

extern "C" void kernel_launch(void* const* d_in, const int* in_sizes, int n_in,
                              void* d_out, int out_size, void* d_ws, size_t ws_size,
                              hipStream_t stream) {
    (void)in_sizes; (void)n_in; (void)out_size; (void)ws_size;
    const float* x     = (const float*)d_in[0];
    const float* hxs   = (const float*)d_in[1];
    const float* masks = (const float*)d_in[2];
    const float* Wconv = (const float*)d_in[3];
    const float* bconv = (const float*)d_in[4];
    const float* Wlin  = (const float*)d_in[5];
    const float* blin  = (const float*)d_in[6];
    float* out = (float*)d_out;

    uint8_t* p = (uint8_t*)d_ws;
    bf16* WxP   = (bf16*)p;   p += (size_t)512 * KH_ * 2;        // 1.18 MB
    bf16* WhP   = (bf16*)p;   p += (size_t)512 * KH_ * 2;        // 1.18 MB
    bf16* Wlp   = (bf16*)p;   p += (size_t)512 * KL_ * 2;        // 6.42 MB
    bf16* xT    = (bf16*)p;   p += (size_t)1024 * S_ * C_ * 2;   // 12.85 MB
    u64*  hxb   = (u64*)p;    p += (size_t)2 * 32 * 1568 * 8;    // 0.80 MB (hx[2])
    float* cbuf = (float*)p;  p += (size_t)B_ * S_ * C_ * 4;     // 0.80 MB
    bf16* chist = (bf16*)p;   p += (size_t)1024 * KL_ * 2;       // 12.85 MB
    bf16* zb    = (bf16*)p;   p += 1024;                         // zero page
    int*  cnt   = (int*)p;    p += 1024;                         // 32 counters

    k_wsplit<<<576, 256, 0, stream>>>(Wconv, WxP, WhP);
    k_wlin2<<<1568, 256, 0, stream>>>(Wlin, Wlp);
    k_xpose<<<3136, 256, 0, stream>>>(x, xT);
    k_hcprep<<<98, 256, 0, stream>>>(hxs, masks, (bf16*)hxb, cbuf);
    k_zero16<<<1, 256, 0, stream>>>((uint4*)zb, 128);            // zb + cnt

    k_persist<<<dim3(256), dim3(512), 0, stream>>>(
        xT, hxb, WxP, WhP, bconv, cbuf, masks, chist,
        out + (size_t)T_ * B_ * HS_, zb, cnt);

    k_lingemm<<<dim3(16, 8), 256, 0, stream>>>(chist, Wlp, blin, out);
}

// Round 12
// 1595.877 us; speedup vs baseline: 1.2284x; 1.2284x over previous
//
#include <hip/hip_runtime.h>
#include <hip/hip_bf16.h>
#include <stdint.h>

#define T_  32
#define B_  32
#define C_  128
#define HS_ 512
#define HW_ 7
#define S_  49
#define CS_  (C_*S_)      // 6272
#define ICS_ (2*C_*S_)    // 12544
#define KH_  1152         // per-half conv K (9*128), kid-major: k = kid*128+ic
#define KL_  6272         // linear K, reordered to k' = s*128+c
#define M_   1568         // B*S
#define MR_  1600
#define N_   512
#define ZROW_ 147         // zero row index in LDS A-tiles (147 rows = 3 batches)

typedef __attribute__((ext_vector_type(8))) short short8;
typedef __attribute__((ext_vector_type(4))) float f32x4;
typedef __hip_bfloat16 bf16;

union bfbits { bf16 b; short s; };

__device__ __forceinline__ void gl16(const void* g, void* l) {
    __builtin_amdgcn_global_load_lds((const __attribute__((address_space(1))) void*)g,
                                     (__attribute__((address_space(3))) void*)l, 16, 0, 0);
}

__device__ __forceinline__ float sigm_f(float v) { return 1.0f / (1.0f + __expf(-v)); }
__device__ __forceinline__ float tanh_f(float v) { return 1.0f - 2.0f / (__expf(2.0f * v) + 1.0f); }
__device__ __forceinline__ float sel4(float r0, float r1, float r2, float r3, int idx) {
    float a = (idx & 1) ? r1 : r0;
    float b = (idx & 1) ? r3 : r2;
    return (idx & 2) ? b : a;
}

// ---------------------------------------------------------------------------
// Fused conv-GEMM + LSTM gates, barrier-free K-loop.
// Tile 64x64, 4 waves (2x2). A (h, and x for mode0) staged ONCE into LDS
// (3 batches = 147 rows + zero row, XOR-swizzled); B (Wx/Wh) per-lane from
// L2-resident global. mode0: C = bias + Ax*Wx + Ah*Wh (stores Gx);
// mode1: C = Gx + Ah*Wh. Epilogue: butterfly gate transpose, cbuf f32 global.
// Dispatch boundary = cross-block h sync (coherent, no atomics).
// ---------------------------------------------------------------------------
__global__ __launch_bounds__(256) void k_fgemm(
    const bf16* __restrict__ xTt, const bf16* __restrict__ hT,
    bf16* __restrict__ hTN,
    const bf16* __restrict__ WxP, const bf16* __restrict__ WhP,
    const float* __restrict__ bconv,
    float* __restrict__ Gx, float* __restrict__ cbuf,
    const float* __restrict__ mask_c, const float* __restrict__ mask_a,
    bf16* __restrict__ chist_t, int mode0)
{
    __shared__ __align__(16) bf16 sH[148 * 128];   // 37888 B
    __shared__ __align__(16) bf16 sX[148 * 128];   // 37888 B

    const int tid = threadIdx.x, lane = tid & 63, w = tid >> 6;
    const int wr = w >> 1, wc = w & 1;
    const int m0 = blockIdx.x * 64, n0 = blockIdx.y * 64;
    const int bA = m0 / S_;                        // base batch of this tile

    // ---- stage A-tiles: 147 rows x 16 chunks, source-side XOR swizzle ------
#pragma unroll
    for (int i = 0; i < 10; ++i) {
        int ci = i * 256 + tid;
        if (ci < 2352) {
            int rl = ci >> 4, q = ci & 15;
            int grow = bA * S_ + rl; if (grow > M_ - 1) grow = M_ - 1;
            gl16(hT + ((size_t)grow << 7) + ((q ^ (rl & 15)) << 3), sH + (size_t)ci * 8);
        }
    }
    if (mode0) {
#pragma unroll
        for (int i = 0; i < 10; ++i) {
            int ci = i * 256 + tid;
            if (ci < 2352) {
                int rl = ci >> 4, q = ci & 15;
                int grow = bA * S_ + rl; if (grow > M_ - 1) grow = M_ - 1;
                gl16(xTt + ((size_t)grow << 7) + ((q ^ (rl & 15)) << 3), sX + (size_t)ci * 8);
            }
        }
    }
    // zero row 147 of both tiles
    if (tid < 16) *(short8*)(sH + ZROW_ * 128 + tid * 8) = short8{0,0,0,0,0,0,0,0};
    else if (tid < 32) *(short8*)(sX + ZROW_ * 128 + (tid - 16) * 8) = short8{0,0,0,0,0,0,0,0};
    asm volatile("s_waitcnt vmcnt(0)" ::: "memory");
    __syncthreads();

    // ---- A-row decode (frag rows = m0 + wr*32 + fm*16 + (lane&15)) ---------
    int rbl[2], ayy[2], axx[2]; bool aok[2];
#pragma unroll
    for (int fm = 0; fm < 2; ++fm) {
        int ra = m0 + wr * 32 + fm * 16 + (lane & 15);
        aok[fm] = ra < M_;
        int rc = aok[fm] ? ra : 0;
        int b = rc / S_, s = rc - b * S_;
        rbl[fm] = (b - bA) * S_;
        ayy[fm] = s / HW_; axx[fm] = s - ayy[fm] * HW_;
    }

    auto ldA = [&](const bf16* buf, int kid, int fm, int kh) -> short8 {
        int ky = kid / 3, kx = kid - 3 * (kid / 3);
        int y2 = ayy[fm] + ky - 1, x2 = axx[fm] + kx - 1;
        bool ok = aok[fm] && (unsigned)y2 < (unsigned)HW_ && (unsigned)x2 < (unsigned)HW_;
        int rl = ok ? rbl[fm] + y2 * HW_ + x2 : ZROW_;
        int chunk = kh * 4 + (lane >> 4);
        return *(const short8*)(buf + rl * 128 + ((chunk ^ (rl & 15)) << 3));
    };
    auto ldW = [&](const bf16* W, int kid, int fn, int kh) -> short8 {
        int col = n0 + wc * 32 + fn * 16 + (lane & 15);
        return *(const short8*)(W + (size_t)col * KH_ + kid * 128 + kh * 32 + ((lane >> 4) << 3));
    };

    auto gemm = [&](const bf16* Abuf, const bf16* W, f32x4 (&acc)[2][2]) {
#pragma unroll
        for (int kid = 0; kid < 9; ++kid) {
            short8 af[2][4], bq[2][4];
#pragma unroll
            for (int kh = 0; kh < 4; ++kh) {
#pragma unroll
                for (int fm = 0; fm < 2; ++fm) af[fm][kh] = ldA(Abuf, kid, fm, kh);
#pragma unroll
                for (int fn = 0; fn < 2; ++fn) bq[fn][kh] = ldW(W, kid, fn, kh);
            }
#pragma unroll
            for (int kh = 0; kh < 4; ++kh)
#pragma unroll
                for (int fm = 0; fm < 2; ++fm)
#pragma unroll
                    for (int fn = 0; fn < 2; ++fn)
                        acc[fm][fn] = __builtin_amdgcn_mfma_f32_16x16x32_bf16(
                            af[fm][kh], bq[fn][kh], acc[fm][fn], 0, 0, 0);
        }
    };

    // ---- accumulate --------------------------------------------------------
    f32x4 accH[2][2];
    if (mode0) {
        f32x4 accX[2][2];
#pragma unroll
        for (int fn = 0; fn < 2; ++fn) {
            int np = n0 + wc * 32 + fn * 16 + (lane & 15);
            float bv = bconv[((np & 3) << 7) + (np >> 2)];
            f32x4 b4 = {bv, bv, bv, bv};
            accX[0][fn] = b4; accX[1][fn] = b4;
            f32x4 z4 = {0.f, 0.f, 0.f, 0.f};
            accH[0][fn] = z4; accH[1][fn] = z4;
        }
        gemm(sX, WxP, accX);
        gemm(sH, WhP, accH);
#pragma unroll
        for (int fm = 0; fm < 2; ++fm) {
            int row = m0 + wr * 32 + fm * 16 + ((lane >> 4) << 2);
#pragma unroll
            for (int fn = 0; fn < 2; ++fn) {
                int col = n0 + wc * 32 + fn * 16 + (lane & 15);
#pragma unroll
                for (int j = 0; j < 4; ++j) {
                    Gx[(size_t)(row + j) * N_ + col] = accX[fm][fn][j];
                    accH[fm][fn][j] += accX[fm][fn][j];
                }
            }
        }
    } else {
#pragma unroll
        for (int fm = 0; fm < 2; ++fm) {
            int row = m0 + wr * 32 + fm * 16 + ((lane >> 4) << 2);
#pragma unroll
            for (int fn = 0; fn < 2; ++fn) {
                int col = n0 + wc * 32 + fn * 16 + (lane & 15);
#pragma unroll
                for (int j = 0; j < 4; ++j)
                    accH[fm][fn][j] = Gx[(size_t)(row + j) * N_ + col];
            }
        }
        gemm(sH, WhP, accH);
    }

    // ---- epilogue: butterfly gate transpose (verified r9-r11) --------------
    const int j = lane & 3;
#pragma unroll
    for (int fm = 0; fm < 2; ++fm) {
        int er = m0 + wr * 32 + fm * 16 + ((lane >> 4) << 2) + (lane & 3);
        bool eok = er < M_;
        int rc = eok ? er : 0;
        int eb = rc / S_, es = rc - eb * S_;
        float mc = mask_c ? mask_c[eb] : 1.f;
        float ma = mask_a ? mask_a[eb] : 1.f;
#pragma unroll
        for (int fn = 0; fn < 2; ++fn) {
            int chn = (n0 >> 2) + wc * 8 + fn * 4 + ((lane & 15) >> 2);
            f32x4 a = accH[fm][fn];
            // round d: lane p sends reg p^d; lane j receives (row rbase+j, gate j^d)
            float s0 = sel4(a[0], a[1], a[2], a[3], j);
            float s1 = __shfl_xor(sel4(a[0], a[1], a[2], a[3], j ^ 1), 1);
            float s2 = __shfl_xor(sel4(a[0], a[1], a[2], a[3], j ^ 2), 2);
            float s3 = __shfl_xor(sel4(a[0], a[1], a[2], a[3], j ^ 3), 3);
            float gi = sel4(s0, s1, s2, s3, j);
            float gf = sel4(s0, s1, s2, s3, j ^ 1);
            float go = sel4(s0, s1, s2, s3, j ^ 2);
            float gg = sel4(s0, s1, s2, s3, j ^ 3);
            float ig = sigm_f(gi), fg = sigm_f(gf), og = sigm_f(go), gv = tanh_f(gg);
            if (eok) {
                size_t ci = (((size_t)(eb * S_ + es)) << 7) + chn;
                float c = cbuf[ci];
                if (mask_c) c *= mc;
                float cn = fg * c + ig * gv;
                cbuf[ci] = cn;
                float hn = og * tanh_f(cn);
                hTN[ci] = __float2bfloat16(hn * ma);
                if (chist_t)
                    chist_t[(size_t)eb * KL_ + es * C_ + chn] = __float2bfloat16(cn);
            }
        }
    }
}

// ---------------------------------------------------------------------------
// Deferred linear: out = relu(chist @ Wlp^T + blin). 64x64 tile, BK=128,
// 3-deep counted-vmcnt pipeline (verified r5-r11).
// ---------------------------------------------------------------------------
#define PIPE_BARRIER_COUNTED()  do {                                   \
    asm volatile("s_waitcnt vmcnt(8)" ::: "memory");                   \
    __builtin_amdgcn_sched_barrier(0);                                 \
    __builtin_amdgcn_s_barrier();                                      \
    __builtin_amdgcn_sched_barrier(0);                                 \
} while (0)
#define PIPE_BARRIER_DRAIN()  do {                                     \
    asm volatile("s_waitcnt vmcnt(0)" ::: "memory");                   \
    __builtin_amdgcn_sched_barrier(0);                                 \
    __builtin_amdgcn_s_barrier();                                      \
    __builtin_amdgcn_sched_barrier(0);                                 \
} while (0)

__global__ __launch_bounds__(256, 1) void k_lingemm(
    const bf16* __restrict__ Ac, const bf16* __restrict__ Wl,
    const float* __restrict__ blin, float* __restrict__ out)
{
    __shared__ __align__(16) uint8_t smem[98304];
    bf16* sA = (bf16*)smem;
    bf16* sB = (bf16*)(smem + 49152);

    const int tid = threadIdx.x, lane = tid & 63, w = tid >> 6;
    const int wr = w >> 1, wc = w & 1;
    const int m0 = blockIdx.x * 64, n0 = blockIdx.y * 64;
    const int kq = tid & 15, rr = tid >> 4;
    const int swz = ((kq ^ rr) << 3);

    f32x4 acc[2][2];
#pragma unroll
    for (int fn = 0; fn < 2; ++fn) {
        int np = n0 + wc * 32 + fn * 16 + (lane & 15);
        float bv = blin[np];
        f32x4 b4 = {bv, bv, bv, bv};
        acc[0][fn] = b4; acc[1][fn] = b4;
    }

    auto stage = [&](int st, int dbuf) {
        bf16* lA = sA + dbuf * 8192;
        bf16* lB = sB + dbuf * 8192;
#pragma unroll
        for (int q = 0; q < 4; ++q) {
            gl16(Ac + (size_t)(m0 + q * 16 + rr) * KL_ + st * 128 + swz, lA + q * 2048 + w * 512);
            gl16(Wl + (size_t)(n0 + q * 16 + rr) * KL_ + st * 128 + swz, lB + q * 2048 + w * 512);
        }
    };
    auto compute = [&](int dbuf) {
        const bf16* lA = sA + dbuf * 8192;
        const bf16* lB = sB + dbuf * 8192;
        short8 af[2][4], bq[2][4];
#pragma unroll
        for (int kh = 0; kh < 4; ++kh) {
            int c = kh * 4 + (lane >> 4);
            int xr = (c ^ (lane & 15)) << 3;
#pragma unroll
            for (int fm = 0; fm < 2; ++fm) {
                int r = wr * 32 + fm * 16 + (lane & 15);
                af[fm][kh] = *(const short8*)(lA + r * 128 + xr);
            }
#pragma unroll
            for (int fn = 0; fn < 2; ++fn) {
                int r = wc * 32 + fn * 16 + (lane & 15);
                bq[fn][kh] = *(const short8*)(lB + r * 128 + xr);
            }
        }
#pragma unroll
        for (int kh = 0; kh < 4; ++kh)
#pragma unroll
            for (int fm = 0; fm < 2; ++fm)
#pragma unroll
                for (int fn = 0; fn < 2; ++fn)
                    acc[fm][fn] = __builtin_amdgcn_mfma_f32_16x16x32_bf16(
                        af[fm][kh], bq[fn][kh], acc[fm][fn], 0, 0, 0);
    };

    stage(0, 0);
    stage(1, 1);
    PIPE_BARRIER_COUNTED();

    int cur = 0;
#pragma unroll 1
    for (int st = 0; st < 49; ++st) {
        int pre = cur + 2; if (pre >= 3) pre -= 3;
        if (st + 2 < 49) stage(st + 2, pre);
        compute(cur);
        if (st + 2 < 49) { PIPE_BARRIER_COUNTED(); }
        else             { PIPE_BARRIER_DRAIN(); }
        ++cur; if (cur == 3) cur = 0;
    }

#pragma unroll
    for (int fm = 0; fm < 2; ++fm)
#pragma unroll
        for (int fn = 0; fn < 2; ++fn) {
            int col = n0 + wc * 32 + fn * 16 + (lane & 15);
            int rb  = m0 + wr * 32 + fm * 16 + ((lane >> 4) << 2);
#pragma unroll
            for (int jj = 0; jj < 4; ++jj)
                out[(size_t)(rb + jj) * N_ + col] = fmaxf(acc[fm][fn][jj], 0.f);
        }
}

// ---------------------------------------------------------------------------
// Weight prep: split Wconv into Wx/Wh, n' = 4c+gate rows, k = kid*128+ic
// ---------------------------------------------------------------------------
__global__ __launch_bounds__(256) void k_wsplit(const float* __restrict__ Wc,
                                               bf16* __restrict__ WxP, bf16* __restrict__ WhP) {
    int idx = blockIdx.x * 256 + threadIdx.x;     // 512*288
    if (idx >= 512 * 288) return;
    int np = idx / 288, kq = idx % 288;
    int oc = ((np & 3) << 7) + (np >> 2);
    int kk = kq * 8;
    int half = kk >= KH_;
    int krel = kk - half * KH_;
    short8 v;
#pragma unroll
    for (int jj = 0; jj < 8; ++jj) {
        int kr = krel + jj;
        int kid = kr >> 7, ic = (kr & 127) + half * 128;
        bfbits bb; bb.b = __float2bfloat16(Wc[((size_t)oc * 256 + ic) * 9 + kid]);
        v[jj] = bb.s;
    }
    bf16* dst = half ? WhP : WxP;
    *reinterpret_cast<short8*>(dst + (size_t)np * KH_ + krel) = v;
}

// Wlin reorder: k' = s*128+c
__global__ __launch_bounds__(256) void k_wlin2(const float* __restrict__ Wl, bf16* __restrict__ Wp) {
    int idx = blockIdx.x * 256 + threadIdx.x;     // 512*784
    if (idx >= 512 * 784) return;
    int np = idx / 784, kq = idx % 784;
    short8 v;
#pragma unroll
    for (int jj = 0; jj < 8; ++jj) {
        int kp = kq * 8 + jj;
        int s = kp >> 7, c = kp & 127;
        bfbits bb; bb.b = __float2bfloat16(Wl[(size_t)np * KL_ + c * S_ + s]);
        v[jj] = bb.s;
    }
    *reinterpret_cast<short8*>(Wp + (size_t)np * KL_ + kq * 8) = v;
}

// x (T*B, C, 49) f32 -> xT (T*B, 49, 128) bf16
__global__ __launch_bounds__(256) void k_xpose(const float* __restrict__ x, bf16* __restrict__ xT) {
    int idx = blockIdx.x * 256 + threadIdx.x;     // 1024*784
    if (idx >= 1024 * 784) return;
    int r = idx / 784;
    int rem = idx % 784;
    int s = rem / 16, c8 = (rem & 15) * 8;
    const float* sp = x + (size_t)r * CS_ + c8 * S_ + s;
    short8 v;
#pragma unroll
    for (int jj = 0; jj < 8; ++jj) { bfbits bb; bb.b = __float2bfloat16(sp[jj * S_]); v[jj] = bb.s; }
    *reinterpret_cast<short8*>(xT + (((size_t)r * S_ + s) << 7) + c8) = v;
}

// h0*mask0 -> hT bf16 (b,s,c);  c0 -> cbuf f32 (b,s,c)
__global__ __launch_bounds__(256) void k_hcprep(const float* __restrict__ hxs,
                                                const float* __restrict__ mask0,
                                                bf16* __restrict__ hT, float* __restrict__ cbuf) {
    int idx = blockIdx.x * 256 + threadIdx.x;     // 32*784
    if (idx >= 32 * 784) return;
    int b = idx / 784;
    int rem = idx % 784;
    int s = rem / 16, c8 = (rem & 15) * 8;
    float m = mask0[b];
    const float* hp = hxs + (size_t)b * ICS_ + c8 * S_ + s;
    const float* cp = hp + CS_;
    size_t o = (((size_t)b * S_ + s) << 7) + c8;
    short8 v;
#pragma unroll
    for (int jj = 0; jj < 8; ++jj) {
        bfbits bb; bb.b = __float2bfloat16(hp[jj * S_] * m); v[jj] = bb.s;
        cbuf[o + jj] = cp[jj * S_];
    }
    *reinterpret_cast<short8*>(hT + o) = v;
}

// final state: out[b][ch][s], ch<128 from hT bf16, else cbuf f32 (both (b,s,c))
__global__ __launch_bounds__(256) void k_final(const bf16* __restrict__ hT, const float* __restrict__ cbuf,
                                               float* __restrict__ out) {
    int i = blockIdx.x * 256 + threadIdx.x;       // 32*12544
    if (i >= B_ * ICS_) return;
    int b = i / ICS_, r = i % ICS_;
    int ch = r / S_, s = r % S_;
    size_t o = (((size_t)b * S_ + s) << 7);
    out[i] = (ch < C_) ? __bfloat162float(hT[o + ch]) : cbuf[o + (ch - C_)];
}

extern "C" void kernel_launch(void* const* d_in, const int* in_sizes, int n_in,
                              void* d_out, int out_size, void* d_ws, size_t ws_size,
                              hipStream_t stream) {
    (void)in_sizes; (void)n_in; (void)out_size; (void)ws_size;
    const float* x     = (const float*)d_in[0];
    const float* hxs   = (const float*)d_in[1];
    const float* masks = (const float*)d_in[2];
    const float* Wconv = (const float*)d_in[3];
    const float* bconv = (const float*)d_in[4];
    const float* Wlin  = (const float*)d_in[5];
    const float* blin  = (const float*)d_in[6];
    float* out = (float*)d_out;

    uint8_t* p = (uint8_t*)d_ws;
    bf16* WxP   = (bf16*)p;   p += (size_t)512 * KH_ * 2;        // 1.18 MB
    bf16* WhP   = (bf16*)p;   p += (size_t)512 * KH_ * 2;        // 1.18 MB
    bf16* Wlp   = (bf16*)p;   p += (size_t)512 * KL_ * 2;        // 6.42 MB
    bf16* xT    = (bf16*)p;   p += (size_t)1024 * S_ * C_ * 2;   // 12.85 MB
    bf16* hA    = (bf16*)p;   p += (size_t)B_ * S_ * C_ * 2;     // 0.40 MB
    bf16* hB    = (bf16*)p;   p += (size_t)B_ * S_ * C_ * 2;     // 0.40 MB
    float* cbuf = (float*)p;  p += (size_t)B_ * S_ * C_ * 4;     // 0.80 MB
    float* Gx   = (float*)p;  p += (size_t)MR_ * N_ * 4;         // 3.28 MB
    bf16* chist = (bf16*)p;   p += (size_t)1024 * KL_ * 2;       // 12.85 MB
    bf16* hbufs[2] = {hA, hB};

    k_wsplit<<<576, 256, 0, stream>>>(Wconv, WxP, WhP);
    k_wlin2<<<1568, 256, 0, stream>>>(Wlin, Wlp);
    k_xpose<<<3136, 256, 0, stream>>>(x, xT);
    k_hcprep<<<98, 256, 0, stream>>>(hxs, masks, hA, cbuf);

    int g = 0;
    for (int t = 0; t < T_; ++t) {
        const bf16* xTt = xT + (size_t)t * B_ * S_ * C_;
        for (int rd = 0; rd < 3; ++rd) {
            const float* mc = (rd == 0) ? masks + (size_t)t * B_ : nullptr;
            const float* ma = (rd == 2 && t < T_ - 1) ? masks + (size_t)(t + 1) * B_ : nullptr;
            bf16* ct = (rd == 2) ? chist + (size_t)t * B_ * KL_ : nullptr;
            k_fgemm<<<dim3(25, 8), 256, 0, stream>>>(
                (rd == 0) ? xTt : nullptr, hbufs[g & 1], hbufs[(g + 1) & 1],
                WxP, WhP, bconv, Gx, cbuf, mc, ma, ct, (rd == 0) ? 1 : 0);
            ++g;
        }
    }

    k_lingemm<<<dim3(16, 8), 256, 0, stream>>>(chist, Wlp, blin, out);
    k_final<<<1568, 256, 0, stream>>>(hbufs[0], cbuf, out + (size_t)T_ * B_ * HS_);
}